// Round 4
// baseline (76872.980 us; speedup 1.0000x reference)
//
#include <hip/hip_runtime.h>
#include <hip/hip_bf16.h>
#include <hip/hip_cooperative_groups.h>

namespace cg = cooperative_groups;

typedef __attribute__((ext_vector_type(8))) short bf16x8;
typedef __attribute__((ext_vector_type(4))) float f32x4;
typedef unsigned short u16;

constexpr int Bb = 64, Ss = 512, Ee = 1024, Hh = 1024, Oo = 50, Gg = 4096;
constexpr int NP = Bb * Oo;              // 3200 (b,o) projection pairs
constexpr int WSTRIDE = 2056;            // shorts per LDS weight row (2048 + 8 pad)
constexpr int LDS_W_BYTES   = 32 * WSTRIDE * 2;          // 131584
constexpr int LDS_GATES_OFF = LDS_W_BYTES;               // 64*33 f32
constexpr int LDS_C_OFF     = LDS_GATES_OFF + 64 * 33 * 4;
constexpr int LDS_BIA_OFF   = LDS_C_OFF + 512 * 4;
constexpr int LDS_TOTAL     = LDS_BIA_OFF + 32 * 4;      // 142208 < 160 KiB

__device__ __forceinline__ float sigf(float x) { return 1.f / (1.f + __expf(-x)); }
__device__ __forceinline__ float bf2f(u16 v) {
    union { unsigned u; float f; } c; c.u = ((unsigned)v) << 16; return c.f;
}
__device__ __forceinline__ u16 f2bf(float x) {
    union { float f; unsigned u; } c; c.f = x;
    unsigned u = c.u + 0x7fffu + ((c.u >> 16) & 1u);   // RNE
    return (u16)(u >> 16);
}

// load 8 consecutive elements (element offset eoff) as bf16x8, from either
// an f32 array (convert, RNE) or a bf16 array (reinterpret).
template<bool F32>
__device__ __forceinline__ bf16x8 load8(const void* base, size_t eoff) {
    if constexpr (F32) {
        const float* p = (const float*)base + eoff;
        float4 a = *(const float4*)p;
        float4 b = *(const float4*)(p + 4);
        bf16x8 r;
        r[0] = (short)f2bf(a.x); r[1] = (short)f2bf(a.y);
        r[2] = (short)f2bf(a.z); r[3] = (short)f2bf(a.w);
        r[4] = (short)f2bf(b.x); r[5] = (short)f2bf(b.y);
        r[6] = (short)f2bf(b.z); r[7] = (short)f2bf(b.w);
        return r;
    } else {
        return *(const bf16x8*)((const u16*)base + eoff);
    }
}
template<bool F32>
__device__ __forceinline__ float loadf(const void* base, size_t i) {
    if constexpr (F32) return ((const float*)base)[i];
    else               return bf2f(((const u16*)base)[i]);
}

// ---------------------------------------------------------------------------
// dtype detector: f32 arrays, viewed as u16, have random mantissa-low halves
// at even indices -> ~0.4% decode as bf16 inf/NaN (bits14..7 all set).
// Genuine bf16 data from N(0, 0.05) can never have exponent 0xFF.
// ---------------------------------------------------------------------------
extern "C" __global__ void detect_mode(const u16* __restrict__ w, int* __restrict__ flag) {
    int hit = 0;
    for (int i = threadIdx.x; i < 4096; i += 64)
        if ((w[2 * i] & 0x7F80u) == 0x7F80u) hit = 1;
    unsigned long long b = __ballot(hit != 0);
    if (threadIdx.x == 0) *flag = (b != 0ULL) ? 1 : 0;
}

// ---------------------------------------------------------------------------
// Fully-fused persistent bidirectional 2-layer LSTM + output projection.
// Phase 0 = forward dir, phase 1 = backward dir. Within a phase:
//   blocks   0..127 : layer-0 chain (input = embedding gathered on the fly)
//   blocks 128..255 : layer-1 chain at 1-step lag (input = layer-0 h ping-pong)
//   all blocks      : per-step output projection at 2-step lag
// h ping-pong: chain-step u writes slot (u+1)&1; consumers read one grid step
// later, when the slot is stable (writer then targets the other slot).
// ---------------------------------------------------------------------------
template<bool F32>
__device__ __forceinline__ void run_bilstm(
        cg::grid_group& grid, char* smem,
        const int* __restrict__ src, const void* __restrict__ emb,
        const void* __restrict__ Wihf, const void* __restrict__ Whhf,
        const void* __restrict__ bf_,
        const void* __restrict__ Wihb, const void* __restrict__ Whhb,
        const void* __restrict__ bb_,
        const void* __restrict__ Wout, const void* __restrict__ bout,
        void* __restrict__ out, float* __restrict__ staging,
        u16* __restrict__ hb) {
    short* Wlds  = (short*)smem;
    float* gates = (float*)(smem + LDS_GATES_OFF);   // [64][33] (+1 pad col)
    float* clds  = (float*)(smem + LDS_C_OFF);       // [512] f32 cell state
    float* blds  = (float*)(smem + LDS_BIA_OFF);     // [32] bias

    const int tid  = threadIdx.x;
    const int blk  = blockIdx.x;
    const int role = blk >> 7;           // 0: layer-0 chain, 1: layer-1 chain
    const int j0   = (blk & 127) * 8;    // owned hidden units j0..j0+7
    const int lane = tid & 63;
    const int wv   = tid >> 6;
    const int mrow = wv * 16 + (lane & 15);   // batch row for A fragment
    const int q8   = (lane >> 4) * 8;         // k-octet for A/B fragments
    const short* wb0 = Wlds + (lane & 15) * WSTRIDE;
    const short* wb1 = Wlds + (16 + (lane & 15)) * WSTRIDE;

    u16* hb0 = hb;                            // [2][Bb*Hh]
    u16* hb1 = hb + 2 * (size_t)Bb * Hh;

    for (int phase = 0; phase < 2; ++phase) {
        const int dir = phase;
        const void* Wih = dir ? Wihb : Wihf;
        const void* Whh = dir ? Whhb : Whhf;
        const void* bia = dir ? bb_  : bf_;
        const size_t wih_off = (size_t)role * Gg * Ee;
        const size_t whh_off = (size_t)role * Gg * Hh;
        const size_t bia_off = (size_t)role * Gg;

        // ---- stage weights: LDS row r -> gate row (r>>3)*Hh + j0 + (r&7)
        for (int c = tid; c < 32 * 256; c += 256) {
            int row  = c >> 8;
            int col8 = (c & 255) * 8;
            int gr   = (row >> 3) * Hh + j0 + (row & 7);
            bf16x8 v = (col8 < Ee)
                ? load8<F32>(Wih, wih_off + (size_t)gr * Ee + col8)
                : load8<F32>(Whh, whh_off + (size_t)gr * Hh + (col8 - Ee));
            *(bf16x8*)((char*)Wlds + row * (WSTRIDE * 2) + col8 * 2) = v;
        }
        if (tid < 32) blds[tid] = loadf<F32>(bia, bia_off + (tid >> 3) * Hh + j0 + (tid & 7));
        for (int i = tid; i < 512; i += 256) clds[i] = 0.f;
        {   // zero my chain's slot-0 h (each block zeroes its own 8 columns)
            u16* hz = role ? hb1 : hb0;
            for (int i = tid; i < 512; i += 256)
                hz[(i >> 3) * Hh + j0 + (i & 7)] = 0;
        }
        __syncthreads();
        __threadfence();
        grid.sync();

        for (int s = 0; s < Ss + 2; ++s) {
            // -------- LSTM step (chain-step u = s - role) --------
            const int u = s - role;
            if (u >= 0 && u < Ss) {
                size_t a0off = 0; const void* a0base = nullptr; bool a0bf = false;
                if (role == 0) {
                    int tsrc = dir ? (Ss - 1 - u) : u;
                    int id   = src[mrow * Ss + tsrc];
                    a0base = emb; a0off = (size_t)id * Ee + q8;
                } else {
                    // h0(u) lives in hb0 slot (u+1)&1 == s&1, stable this step
                    a0base = hb0; a0off = (size_t)(s & 1) * Bb * Hh + (size_t)mrow * Hh + q8;
                    a0bf = true;
                }
                u16* myhb = role ? hb1 : hb0;
                const u16* ar1 = myhb + (size_t)(u & 1) * Bb * Hh + (size_t)mrow * Hh + q8;
                u16* hnext     = myhb + (size_t)((u + 1) & 1) * Bb * Hh;

                f32x4 acc0 = {0.f, 0.f, 0.f, 0.f};
                f32x4 acc1 = {0.f, 0.f, 0.f, 0.f};
                for (int ks = 0; ks < Ee; ks += 32) {
                    bf16x8 a = a0bf ? *(const bf16x8*)((const u16*)a0base + a0off + ks)
                                    : load8<F32>(a0base, a0off + ks);
                    bf16x8 b0 = *(const bf16x8*)(wb0 + ks + q8);
                    bf16x8 b1 = *(const bf16x8*)(wb1 + ks + q8);
                    acc0 = __builtin_amdgcn_mfma_f32_16x16x32_bf16(a, b0, acc0, 0, 0, 0);
                    acc1 = __builtin_amdgcn_mfma_f32_16x16x32_bf16(a, b1, acc1, 0, 0, 0);
                }
                for (int ks = 0; ks < Hh; ks += 32) {
                    bf16x8 a  = *(const bf16x8*)(ar1 + ks);
                    bf16x8 b0 = *(const bf16x8*)(wb0 + Ee + ks + q8);
                    bf16x8 b1 = *(const bf16x8*)(wb1 + Ee + ks + q8);
                    acc0 = __builtin_amdgcn_mfma_f32_16x16x32_bf16(a, b0, acc0, 0, 0, 0);
                    acc1 = __builtin_amdgcn_mfma_f32_16x16x32_bf16(a, b1, acc1, 0, 0, 0);
                }
                // C/D layout: col = lane&15 (gate col n), row = (lane>>4)*4+reg (batch)
                {
                    int c0 = lane & 15;
                    int rb = wv * 16 + (lane >> 4) * 4;
#pragma unroll
                    for (int r = 0; r < 4; ++r) {
                        gates[(rb + r) * 33 + c0]      = acc0[r] + blds[c0];
                        gates[(rb + r) * 33 + 16 + c0] = acc1[r] + blds[16 + c0];
                    }
                }
                __syncthreads();
                // cell update: 512 (b, j) pairs; gate n: [0,8)=i [8,16)=f [16,24)=g [24,32)=o
#pragma unroll
                for (int q = 0; q < 2; ++q) {
                    int idx = tid + q * 256;
                    int b = idx >> 3, j = idx & 7;
                    float gi = gates[b * 33 + j];
                    float gf = gates[b * 33 + 8 + j];
                    float gg = gates[b * 33 + 16 + j];
                    float go = gates[b * 33 + 24 + j];
                    float cc = clds[idx];
                    float ct = sigf(gf) * cc + sigf(gi) * tanhf(gg);
                    float ht = sigf(go) * tanhf(ct);
                    clds[idx] = ct;
                    hnext[b * Hh + j0 + j] = f2bf(ht);
                }
            }
            // -------- fused output projection (lag 2: up = s-2) --------
            const int up = s - 2;
            if (up >= 0 && up < Ss) {
                // h1(up) lives in hb1 slot (up+1)&1 == (s-1)&1, stable this step
                const u16* hsrc = hb1 + (size_t)((s - 1) & 1) * Bb * Hh;
                for (int w = wv; w < 13; w += 4) {
                    int p = blk + (w << 8);
                    if (p >= NP) break;
                    int b = p / Oo, o = p - b * Oo;
                    const u16* hrow = hsrc + (size_t)b * Hh + lane * 16;
                    bf16x8 hv0 = *(const bf16x8*)(hrow);
                    bf16x8 hv1 = *(const bf16x8*)(hrow + 8);
                    size_t woff = (size_t)o * (2 * Hh) + (size_t)phase * Hh + lane * 16;
                    bf16x8 wv0 = load8<F32>(Wout, woff);
                    bf16x8 wv1 = load8<F32>(Wout, woff + 8);
                    float acc = 0.f;
#pragma unroll
                    for (int k = 0; k < 8; ++k)
                        acc += bf2f((u16)hv0[k]) * bf2f((u16)wv0[k])
                             + bf2f((u16)hv1[k]) * bf2f((u16)wv1[k]);
#pragma unroll
                    for (int m = 32; m; m >>= 1) acc += __shfl_xor(acc, m, 64);
                    if (lane == 0) {
                        if (phase == 0) {
                            staging[(size_t)up * NP + p] = acc;       // t = up (fwd)
                        } else {
                            int t = Ss - 1 - up;                      // bwd scan -> orig t
                            float tot = staging[(size_t)t * NP + p] + acc
                                      + loadf<F32>(bout, o);
                            size_t oidx = (size_t)b * Ss * Oo + (size_t)t * Oo + o;
                            if constexpr (F32) ((float*)out)[oidx] = tot;
                            else               ((u16*)out)[oidx]   = f2bf(tot);
                        }
                    }
                }
            }
            __threadfence();
            grid.sync();
        }
    }
}

extern "C" __global__ void __launch_bounds__(256, 1)
bilstm_fused(const int* __restrict__ src, const void* __restrict__ emb,
             const void* __restrict__ Wihf, const void* __restrict__ Whhf,
             const void* __restrict__ bf_,
             const void* __restrict__ Wihb, const void* __restrict__ Whhb,
             const void* __restrict__ bb_,
             const void* __restrict__ Wout, const void* __restrict__ bout,
             void* __restrict__ out, float* __restrict__ staging,
             u16* __restrict__ hb, const int* __restrict__ mode_flag) {
    cg::grid_group grid = cg::this_grid();
    extern __shared__ char smem[];
    const int mode = *(const volatile int*)mode_flag;
    if (mode)
        run_bilstm<true >(grid, smem, src, emb, Wihf, Whhf, bf_, Wihb, Whhb, bb_,
                          Wout, bout, out, staging, hb);
    else
        run_bilstm<false>(grid, smem, src, emb, Wihf, Whhf, bf_, Wihb, Whhb, bb_,
                          Wout, bout, out, staging, hb);
}

// ---------------------------------------------------------------------------
extern "C" void kernel_launch(void* const* d_in, const int* in_sizes, int n_in,
                              void* d_out, int out_size, void* d_ws, size_t ws_size,
                              hipStream_t stream) {
    const int*  src  = (const int*)d_in[0];
    const void* emb  = d_in[1];
    const void* Wihf = d_in[2];
    const void* Whhf = d_in[3];
    const void* bf_  = d_in[4];
    const void* Wihb = d_in[5];
    const void* Whhb = d_in[6];
    const void* bb_  = d_in[7];
    const void* Wout = d_in[8];
    const void* bout = d_in[9];
    void* out = d_out;

    char* ws = (char*)d_ws;
    float* staging = (float*)ws;                                   // 512*3200*4 = 6,553,600 B
    u16*   hb      = (u16*)(ws + (size_t)Ss * NP * 4);             // 4*64*1024*2 = 524,288 B
    int*   mflag   = (int*)(ws + (size_t)Ss * NP * 4 + 4 * (size_t)Bb * Hh * 2);

    detect_mode<<<dim3(1), dim3(64), 0, stream>>>((const u16*)Wihf, mflag);

    hipFuncSetAttribute((const void*)bilstm_fused,
                        hipFuncAttributeMaxDynamicSharedMemorySize, LDS_TOTAL);
    void* args[] = { (void*)&src, (void*)&emb,
                     (void*)&Wihf, (void*)&Whhf, (void*)&bf_,
                     (void*)&Wihb, (void*)&Whhb, (void*)&bb_,
                     (void*)&Wout, (void*)&bout,
                     (void*)&out, (void*)&staging, (void*)&hb, (void*)&mflag };
    hipLaunchCooperativeKernel((void*)bilstm_fused, dim3(256), dim3(256),
                               args, (unsigned)LDS_TOTAL, stream);
}